// Round 5
// baseline (518.745 us; speedup 1.0000x reference)
//
#include <hip/hip_runtime.h>
#include <stdint.h>

#define NGRAPH 2048
#define MNODES 128
#define HID 256
#define OUTC 12
#define NEDGE 2097152
#define NSUB 16     // sub-buckets per graph, keyed by blockIdx&15 (XCD-affine)
#define SUBCAP 160  // per-sub capacity (mean 64, sd ~8 -> 12 sd margin)
#define CURPAD 16   // cursor stride in uints (64B: one cache line per cursor)

typedef __attribute__((ext_vector_type(8))) short short8;
typedef __attribute__((ext_vector_type(4))) float v4f;
typedef __attribute__((ext_vector_type(2))) float v2f;

#define SLICE 64        // hidden columns per block
#define SWT_STRIDE 136  // node-dim stride (136 elem = 272 B, 16B-aligned, bank-friendly)

// packed f32x2 -> bf16x2, round-to-nearest-even (identical numerics to manual RNE)
__device__ __forceinline__ unsigned int cvtpk_bf16(float lo, float hi) {
    unsigned int r;
    asm("v_cvt_pk_bf16_f32 %0, %1, %2" : "=v"(r) : "v"(lo), "v"(hi));
    return r;
}
// CDNA packed fp32: both halves in one instruction (full-rate dual FP32)
__device__ __forceinline__ v2f pk_mul(v2f a, v2f b) {
    v2f r; asm("v_pk_mul_f32 %0, %1, %2" : "=v"(r) : "v"(a), "v"(b)); return r;
}
__device__ __forceinline__ v2f pk_add(v2f a, v2f b) {
    v2f r; asm("v_pk_add_f32 %0, %1, %2" : "=v"(r) : "v"(a), "v"(b)); return r;
}

// ---- stage 1: bucket edges by (graph, blockIdx&15).
// Cursors padded to 64B (own line each); sub-bucket writers share an XCD.
__global__ void scatter_edges(const int* __restrict__ ei,
                              unsigned int* __restrict__ buckets,
                              unsigned int* __restrict__ cursors) {
    int e = blockIdx.x * blockDim.x + threadIdx.x;
    if (e >= NEDGE) return;
    int sub = blockIdx.x & (NSUB - 1);
    int sN = ei[e];
    int dN = ei[NEDGE + e];
    int g = sN >> 7;
    unsigned int slot = atomicAdd(&cursors[(g * NSUB + sub) * CURPAD], 1u);
    if (slot < SUBCAP)
        buckets[((size_t)g * NSUB + sub) * SUBCAP + slot] =
            (unsigned)(sN & 127) | ((unsigned)(dN & 127) << 8);
}

// ---- fallback (tiny ws): direct global atomicOr build (needs bits pre-zeroed)
__global__ void build_bits(const int* __restrict__ ei, unsigned int* __restrict__ bits) {
    int e = blockIdx.x * blockDim.x + threadIdx.x;
    if (e >= NEDGE) return;
    int sN = ei[e];
    int dN = ei[NEDGE + e];
    int g = sN >> 7;
    int li = sN & 127;
    int lj = dN & 127;
    unsigned int* base = bits + (size_t)g * (MNODES * 4);
    atomicOr(&base[li * 4 + (lj >> 5)], 1u << (lj & 31));
    atomicOr(&base[lj * 4 + (li >> 5)], 1u << (li & 31));
}

// ---- walk kernel with FUSED adjacency build: block = (graph, 64-col slice).
// Prologue builds the graph's 2KB bitmask in LDS from the bucket list (LDS
// atomicOr), aliased onto sWT[1] (first written only after the init barrier).
// 4 waves; wave w owns rows (w>>1)*64..+63, cols (w&1)*32..+31 of the slice.
// A fragments live in registers for all 5 iterations; walk^T double-buffers
// through LDS (1 barrier/iter).
// launch_bounds(256,3): cap 170 regs; kernel needs ~150. (256,4)=cap128
// spilled 262MB scratch, (256,5)=cap102 spilled 1.8GB (rounds 1-2).
__launch_bounds__(256, 3)
__global__ void walk2(const float* __restrict__ x,
                      const float* __restrict__ W,
                      const unsigned int* __restrict__ buckets,
                      const unsigned int* __restrict__ cursors,
                      const unsigned int* __restrict__ Abits,
                      int use_bucket,
                      float* __restrict__ partial) {
    __shared__ __align__(16) unsigned short sWT[2][SLICE][SWT_STRIDE];  // walk^T: [buf][col][node]
    __shared__ float sVs2[2][6][SLICE];                                 // per-row-half col sums

    const int bx = blockIdx.x;
    const int g = bx >> 2;
    const int s = bx & 3;
    const int tid = threadIdx.x;
    const int wave = tid >> 6;
    const int lane = tid & 63;
    const int lrow = lane & 15;
    const int quad = lane >> 4;
    const int rhalf = wave >> 1;
    const int r0 = rhalf * 64;
    const int c0 = (wave & 1) * 32;      // col base within slice
    const int cg0 = s * SLICE + c0;      // global col base

    // ---- A fragments -> registers (fixed across iterations)
    short8 areg[4][4];  // [rt][ks]
    if (use_bucket) {
        // sb aliases sWT[1]: all sb reads complete before the init barrier;
        // sWT[1] is first written in iteration 1 (after it).
        unsigned int* sb = (unsigned int*)&sWT[1][0][0];  // 512 uints = 2KB
        for (int i = tid; i < MNODES * 4; i += 256) sb[i] = 0;
        __syncthreads();
        {
            int sub = tid >> 4;   // 16 threads per sub-bucket
            int i0 = tid & 15;
            unsigned int n = cursors[(g * NSUB + sub) * CURPAD];
            if (n > SUBCAP) n = SUBCAP;
            const unsigned int* bk = buckets + ((size_t)g * NSUB + sub) * SUBCAP;
            for (unsigned int i = i0; i < n; i += 16) {
                unsigned int p = bk[i];
                int li = p & 127;
                int lj = (p >> 8) & 127;
                atomicOr(&sb[li * 4 + (lj >> 5)], 1u << (lj & 31));
                atomicOr(&sb[lj * 4 + (li >> 5)], 1u << (li & 31));
            }
        }
        __syncthreads();
#pragma unroll
        for (int rt = 0; rt < 4; rt++) {
            int row = r0 + rt * 16 + lrow;
            uint4 w4 = *(const uint4*)&sb[row * 4];   // ds_read_b128, quad-broadcast
#pragma unroll
            for (int ks = 0; ks < 4; ks++) {
                unsigned int w = (ks == 0 ? w4.x : ks == 1 ? w4.y : ks == 2 ? w4.z : w4.w) >> (quad * 8);
                short8 a;
#pragma unroll
                for (int j = 0; j < 8; j++)
                    a[j] = (short)(((w >> j) & 1u) ? 0x3F80 : 0);
                areg[rt][ks] = a;
            }
        }
    } else {
        const uint4* Bg = (const uint4*)(Abits + (size_t)g * (MNODES * 4));
#pragma unroll
        for (int rt = 0; rt < 4; rt++) {
            uint4 w4 = Bg[r0 + rt * 16 + lrow];
#pragma unroll
            for (int ks = 0; ks < 4; ks++) {
                unsigned int w = (ks == 0 ? w4.x : ks == 1 ? w4.y : ks == 2 ? w4.z : w4.w) >> (quad * 8);
                short8 a;
#pragma unroll
                for (int j = 0; j < 8; j++)
                    a[j] = (short)(((w >> j) & 1u) ? 0x3F80 : 0);
                areg[rt][ks] = a;
            }
        }
    }

    // ---- X fragments (fp32 pairs, C-layout), init walk1 = X (buf 0), v1 sums
    v2f xf2[4][2][2];   // [rt][ct][rows 0-1 / 2-3]
    const float* xg = x + (size_t)g * (MNODES * HID);
#pragma unroll
    for (int rt = 0; rt < 4; rt++)
#pragma unroll
        for (int ct = 0; ct < 2; ct++) {
            int col = cg0 + ct * 16 + lrow;
            int row = r0 + rt * 16 + quad * 4;
            float l0 = xg[(row + 0) * HID + col];
            float l1 = xg[(row + 1) * HID + col];
            float l2 = xg[(row + 2) * HID + col];
            float l3 = xg[(row + 3) * HID + col];
            xf2[rt][ct][0] = (v2f){l0, l1};
            xf2[rt][ct][1] = (v2f){l2, l3};
        }
#pragma unroll
    for (int ct = 0; ct < 2; ct++) {
        int lcol = c0 + ct * 16 + lrow;
        v2f csp = (v2f)(0.0f);
#pragma unroll
        for (int rt = 0; rt < 4; rt++) {
            int nbase = r0 + rt * 16 + quad * 4;
            uint2 u;
            u.x = cvtpk_bf16(xf2[rt][ct][0][0], xf2[rt][ct][0][1]);
            u.y = cvtpk_bf16(xf2[rt][ct][1][0], xf2[rt][ct][1][1]);
            *(uint2*)&sWT[0][lcol][nbase] = u;
            csp = pk_add(csp, pk_add(xf2[rt][ct][0], xf2[rt][ct][1]));
        }
        float cs = csp[0] + csp[1];
        cs += __shfl_xor(cs, 16);
        cs += __shfl_xor(cs, 32);
        if (quad == 0) sVs2[rhalf][0][lcol] = cs;   // same-rhalf waves own disjoint lcol
    }
    __syncthreads();

    // ---- 5 iterations: Y = A@walk (MFMA, A from regs), walk = Y.*X, col sums.
    // Double-buffered sWT: read buf cur, write buf nxt -> ONE barrier per iter.
    for (int it = 1; it <= 5; it++) {
        const int cur = (it - 1) & 1;
        const int nxt = it & 1;
        v4f acc[4][2];
#pragma unroll
        for (int rt = 0; rt < 4; rt++)
#pragma unroll
            for (int ct = 0; ct < 2; ct++) acc[rt][ct] = (v4f)(0.0f);
        __builtin_amdgcn_s_setprio(1);
#pragma unroll
        for (int ks = 0; ks < 4; ks++) {
            int k0 = ks * 32 + quad * 8;
#pragma unroll
            for (int ct = 0; ct < 2; ct++) {
                short8 bf = *(const short8*)&sWT[cur][c0 + ct * 16 + lrow][k0];
#pragma unroll
                for (int rt = 0; rt < 4; rt++)
                    acc[rt][ct] = __builtin_amdgcn_mfma_f32_16x16x32_bf16(areg[rt][ks], bf, acc[rt][ct], 0, 0, 0);
            }
        }
        __builtin_amdgcn_s_setprio(0);
#pragma unroll
        for (int ct = 0; ct < 2; ct++) {
            int lcol = c0 + ct * 16 + lrow;
            v2f csp = (v2f)(0.0f);
#pragma unroll
            for (int rt = 0; rt < 4; rt++) {
                v2f nw01 = pk_mul(__builtin_shufflevector(acc[rt][ct], acc[rt][ct], 0, 1), xf2[rt][ct][0]);
                v2f nw23 = pk_mul(__builtin_shufflevector(acc[rt][ct], acc[rt][ct], 2, 3), xf2[rt][ct][1]);
                int nbase = r0 + rt * 16 + quad * 4;
                uint2 u;
                u.x = cvtpk_bf16(nw01[0], nw01[1]);
                u.y = cvtpk_bf16(nw23[0], nw23[1]);
                *(uint2*)&sWT[nxt][lcol][nbase] = u;
                csp = pk_add(csp, pk_add(nw01, nw23));
            }
            float cs = csp[0] + csp[1];
            cs += __shfl_xor(cs, 16);
            cs += __shfl_xor(cs, 32);
            if (quad == 0) sVs2[rhalf][it][lcol] = cs;
        }
        __syncthreads();  // next-iter buffer ready (also publishes sVs2)
    }

    // ---- per-block partial projection over this 6x64 slice of vs.
    // All 4 waves participate: 3 output channels each.
    {
        int cbase = wave * 3;
#pragma unroll
        for (int cc = 0; cc < 3; cc++) {
            int c = cbase + cc;
            const float* wr = W + c * (6 * HID) + s * SLICE;
            float p = 0.0f;
#pragma unroll
            for (int k = 0; k < 6; k++) {
                float v = sVs2[0][k][lane] + sVs2[1][k][lane];
                p += v * wr[k * HID + lane];
            }
#pragma unroll
            for (int off = 32; off >= 1; off >>= 1) p += __shfl_down(p, off);
            if (lane == 0) partial[bx * OUTC + c] = p;
        }
    }
}

// ---- combine the 4 slice partials + bias
__global__ void combine(const float* __restrict__ partial, const float* __restrict__ bvec,
                        float* __restrict__ out) {
    int i = blockIdx.x * blockDim.x + threadIdx.x;
    if (i >= NGRAPH * OUTC) return;
    int c = i % OUTC;
    int g = i / OUTC;
    float p = bvec[c];
#pragma unroll
    for (int s = 0; s < 4; s++) p += partial[(g * 4 + s) * OUTC + c];
    out[i] = p;
}

extern "C" void kernel_launch(void* const* d_in, const int* in_sizes, int n_in,
                              void* d_out, int out_size, void* d_ws, size_t ws_size,
                              hipStream_t stream) {
    const float* x = (const float*)d_in[0];
    const float* W = (const float*)d_in[1];
    const float* b = (const float*)d_in[2];
    const int* ei = (const int*)d_in[4];
    float* out = (float*)d_out;

    const size_t BUCKETS = (size_t)NGRAPH * NSUB * SUBCAP * sizeof(unsigned int);   // 21 MB
    const size_t CURS    = (size_t)NGRAPH * NSUB * CURPAD * sizeof(unsigned int);   // 2 MB
    const size_t BITS    = (size_t)NGRAPH * MNODES * 4 * sizeof(unsigned int);      // 4 MB
    const size_t PARTIAL = (size_t)NGRAPH * 4 * OUTC * sizeof(float);               // 384 KB

    if (ws_size >= BUCKETS + CURS + PARTIAL) {
        unsigned int* buckets = (unsigned int*)d_ws;
        unsigned int* cursors = (unsigned int*)((char*)d_ws + BUCKETS);
        float* partial        = (float*)((char*)d_ws + BUCKETS + CURS);
        hipMemsetAsync(cursors, 0, CURS, stream);
        scatter_edges<<<NEDGE / 256, 256, 0, stream>>>(ei, buckets, cursors);
        walk2<<<NGRAPH * 4, 256, 0, stream>>>(x, W, buckets, cursors, nullptr, 1, partial);
        combine<<<(NGRAPH * OUTC + 255) / 256, 256, 0, stream>>>(partial, b, out);
    } else {
        unsigned int* bits = (unsigned int*)d_ws;   // 4 MB
        float* partial = (float*)((char*)d_ws + BITS);
        hipMemsetAsync(bits, 0, BITS, stream);
        build_bits<<<NEDGE / 512, 512, 0, stream>>>(ei, bits);
        walk2<<<NGRAPH * 4, 256, 0, stream>>>(x, W, nullptr, nullptr, bits, 0, partial);
        combine<<<(NGRAPH * OUTC + 255) / 256, 256, 0, stream>>>(partial, b, out);
    }
}